// Round 7
// baseline (374.220 us; speedup 1.0000x reference)
//
#include <hip/hip_runtime.h>
#include <hip/hip_bf16.h>

// ---------------------------------------------------------------------------
// WeightOnlyBlockwiseQuantizedLinear: out[m][n] = sum_s scaler[s][n] *
//   sum_{c<128} W[s][c][n] * x[m][s*128+c],  m = b*D+d (2048), n (4096)
//
// R7: two dispatches only.
//  - prep_b: W int32 [K][N] * scaler -> bf16 B^T [N][K] (register transpose).
//  - gemm:   R2-proven 128x128 single-buffer MFMA core, with x fp32->bf16
//            conversion FUSED into A-staging (v_cvt_pk_bf16_f32 + swizzled
//            ds_write_b128). prep_a eliminated (one less dispatch, -50 MB ws).
// Rationale: R3/R4/R6 schedule rewrites all landed at 33% MfmaUtil == R2;
// the unattributed ~130 us outside the gemm is the bigger lever.
// ---------------------------------------------------------------------------

#define MDIM 2048
#define NDIM 4096
#define KDIM 4096
#define NBLK 32
#define BM 128
#define BN 128
#define BK 64
#define NT (KDIM / BK)

typedef __attribute__((ext_vector_type(8))) short bf16x8;
typedef __attribute__((ext_vector_type(4))) float f32x4;
typedef __attribute__((ext_vector_type(8))) unsigned short u16x8;
typedef __attribute__((ext_vector_type(4))) unsigned int u32x4;

__device__ __forceinline__ unsigned short f2bf(float f) {
  unsigned u = __float_as_uint(f);
  u += 0x7fffu + ((u >> 16) & 1u);   // round-to-nearest-even
  return (unsigned short)(u >> 16);
}

__device__ __forceinline__ void gl_lds16(const void* g, void* l) {
  __builtin_amdgcn_global_load_lds(
      (const __attribute__((address_space(1))) unsigned int*)g,
      (__attribute__((address_space(3))) unsigned int*)l,
      16, 0, 0);
}

// ---- prep B: W int32 [K][N] * scaler -> bf16 W^T [N][K] -------------------
// Zero-LDS register 8x8 transpose; coalesced reads (16 rows x 128 B contiguous
// per wave per step) and writes (256 B contiguous runs).
__global__ __launch_bounds__(256, 4)
void prep_b_kernel(const int* __restrict__ w,
                   const float* __restrict__ scaler,
                   unsigned short* __restrict__ bt) {
  const int t = threadIdx.x;
  const int n0 = blockIdx.x * 128;
  const int k0 = blockIdx.y * 128;
  const int s = blockIdx.y;            // 128-k tile == one scaler block
  const int k8 = (t & 15) * 8;
  const int n8 = (t >> 4) * 8;

  float sc[8];
  {
    const float4* scv = reinterpret_cast<const float4*>(scaler + (size_t)s * NDIM + n0 + n8);
    const float4 s0 = scv[0], s1 = scv[1];
    sc[0] = s0.x; sc[1] = s0.y; sc[2] = s0.z; sc[3] = s0.w;
    sc[4] = s1.x; sc[5] = s1.y; sc[6] = s1.z; sc[7] = s1.w;
  }
  u16x8 outv[8];
#pragma unroll
  for (int r = 0; r < 8; ++r) {
    const int4* src = reinterpret_cast<const int4*>(w + (size_t)(k0 + k8 + r) * NDIM + n0 + n8);
    const int4 a = src[0], b = src[1];
    const int v[8] = {a.x, a.y, a.z, a.w, b.x, b.y, b.z, b.w};
#pragma unroll
    for (int j = 0; j < 8; ++j) outv[j][r] = f2bf((float)v[j] * sc[j]);
  }
#pragma unroll
  for (int j = 0; j < 8; ++j)
    *reinterpret_cast<u16x8*>(bt + (size_t)(n0 + n8 + j) * KDIM + k0 + k8) = outv[j];
}

// ---- fused GEMM: R2 core + in-kernel A conversion -------------------------
#define MFMA_BF16 __builtin_amdgcn_mfma_f32_16x16x32_bf16

__global__ __launch_bounds__(256, 3)
void gemm_kernel(const float* __restrict__ x,
                 const unsigned short* __restrict__ bt,
                 float* __restrict__ out) {
  __shared__ __align__(16) char lds[32768];   // A 16K | B 16K

  const int t = threadIdx.x;
  const int lane = t & 63;
  const int wid = t >> 6;
  const int wm = wid >> 1;        // 0..1
  const int wn = wid & 1;         // 0..1
  const int lane15 = lane & 15;
  const int laneq = lane >> 4;    // 0..3
  const int swz = (lane & 7) << 4;

  // XCD-aware block swizzle (512 % 8 == 0 -> bijective)
  const unsigned flat = blockIdx.x;
  const unsigned swzb = (flat & 7u) * 64u + (flat >> 3);
  const int ntile = swzb & 31;
  const int mtile = swzb >> 5;
  const int m0 = mtile * BM;
  const int n0 = ntile * BN;

  char* const lA = lds;            // [128][64] bf16, byte (row*128+k*2)^((row&7)<<4)
  char* const lB = lds + 16384;    // [128][64] bf16, same swizzle

  // ---- A staging (fused fp32->bf16): thread covers rows arow+32p, chunk achk
  const int arow = t >> 3;        // 0..31
  const int achk = t & 7;         // 8-float chunk along k
  const float* gx = x + (size_t)(m0 + arow) * KDIM + achk * 8;
  const int aswz = (arow & 7) << 4;   // row&7 invariant under +32p
  int aoff[4];
#pragma unroll
  for (int p = 0; p < 4; ++p)
    aoff[p] = (((arow + p * 32) * 128) + achk * 16) ^ aswz;

  // ---- B staging via global_load_lds, pre-swizzled global source
  const int srow = t >> 3;                    // 0..31
  const int sslot = (t & 7) ^ (srow & 7);     // inverse of read-side XOR
  const char* gb = (const char*)bt + ((size_t)(n0 + srow) * KDIM) * 2 + sslot * 16;
  const size_t rstepB = (size_t)32 * KDIM * 2;
  char* const lbst = lB + wid * 1024;         // wave-uniform dest base

  int offA[4], offB[4];
#pragma unroll
  for (int i = 0; i < 4; ++i) {
    offA[i] = (wm * 64 + i * 16 + lane15) * 128 + laneq * 16;
    offB[i] = (wn * 64 + i * 16 + lane15) * 128 + laneq * 16;
  }

  const f32x4 fzero = {0.f, 0.f, 0.f, 0.f};
  f32x4 acc[4][4];
#pragma unroll
  for (int m = 0; m < 4; ++m)
#pragma unroll
    for (int n = 0; n < 4; ++n) acc[m][n] = fzero;

  for (int kt = 0; kt < NT; ++kt) {
    // ---- stage A: 8x float4 -> cvt_pk -> 4x swizzled ds_write_b128
    float4 va[4][2];
#pragma unroll
    for (int p = 0; p < 4; ++p) {
      const float* src = gx + (size_t)p * 32 * KDIM + kt * 64;
      va[p][0] = *reinterpret_cast<const float4*>(src);
      va[p][1] = *reinterpret_cast<const float4*>(src + 4);
    }
#pragma unroll
    for (int p = 0; p < 4; ++p) {
      unsigned d0, d1, d2, d3;
      asm("v_cvt_pk_bf16_f32 %0, %1, %2" : "=v"(d0) : "v"(va[p][0].x), "v"(va[p][0].y));
      asm("v_cvt_pk_bf16_f32 %0, %1, %2" : "=v"(d1) : "v"(va[p][0].z), "v"(va[p][0].w));
      asm("v_cvt_pk_bf16_f32 %0, %1, %2" : "=v"(d2) : "v"(va[p][1].x), "v"(va[p][1].y));
      asm("v_cvt_pk_bf16_f32 %0, %1, %2" : "=v"(d3) : "v"(va[p][1].z), "v"(va[p][1].w));
      u32x4 wv = {d0, d1, d2, d3};
      *reinterpret_cast<u32x4*>(lA + aoff[p]) = wv;
    }
    // ---- stage B: 4x global_load_lds (16 B/lane)
    const size_t kob = (size_t)kt * (BK * 2);
#pragma unroll
    for (int j = 0; j < 4; ++j)
      gl_lds16(gb + kob + j * rstepB, lbst + j * 4096);

    __syncthreads();   // drains vmcnt+lgkm: A writes visible, B loads landed

#pragma unroll
    for (int tt = 0; tt < 2; ++tt) {
      bf16x8 af[4], bf[4];
#pragma unroll
      for (int i = 0; i < 4; ++i) {
        af[i] = *(const bf16x8*)(lA + ((offA[i] + tt * 64) ^ swz));
        bf[i] = *(const bf16x8*)(lB + ((offB[i] + tt * 64) ^ swz));
      }
#pragma unroll
      for (int m = 0; m < 4; ++m)
#pragma unroll
        for (int n = 0; n < 4; ++n)
          acc[m][n] = MFMA_BF16(af[m], bf[n], acc[m][n], 0, 0, 0);
    }
    __syncthreads();   // all waves done reading before restage
  }

  // epilogue: C/D layout col=lane&15, row=(lane>>4)*4+reg  [m89-verified]
#pragma unroll
  for (int m = 0; m < 4; ++m)
#pragma unroll
    for (int r = 0; r < 4; ++r) {
      const int row = m0 + wm * 64 + m * 16 + laneq * 4 + r;
      float* op = out + (size_t)row * NDIM + n0 + wn * 64 + lane15;
#pragma unroll
      for (int n = 0; n < 4; ++n) op[n * 16] = acc[m][n][r];
    }
}

// ---- correct-but-slow fallback if ws is too small -------------------------
__global__ void fallback_kernel(const float* __restrict__ x,
                                const int* __restrict__ w,
                                const float* __restrict__ scaler,
                                float* __restrict__ out) {
  const int n = blockIdx.x * 256 + threadIdx.x;
  const int m = blockIdx.y;
  float acc = 0.f;
  for (int s = 0; s < NBLK; ++s) {
    float p = 0.f;
    const float* xr = x + (size_t)m * KDIM + s * 128;
    const int* wr = w + (size_t)s * 128 * NDIM + n;
#pragma unroll 8
    for (int c = 0; c < 128; ++c) p += xr[c] * (float)wr[(size_t)c * NDIM];
    acc += p * scaler[s * NDIM + n];
  }
  out[(size_t)m * NDIM + n] = acc;
}

extern "C" void kernel_launch(void* const* d_in, const int* in_sizes, int n_in,
                              void* d_out, int out_size, void* d_ws, size_t ws_size,
                              hipStream_t stream) {
  (void)in_sizes; (void)n_in; (void)out_size;
  const float* x = (const float*)d_in[0];
  const int* w = (const int*)d_in[1];        // int8 values, int32 storage
  const float* sc = (const float*)d_in[2];
  float* out = (float*)d_out;

  const size_t need = (size_t)NDIM * KDIM * 2;   // 33.6 MB B^T only
  if (ws_size >= need) {
    unsigned short* bt = (unsigned short*)d_ws;  // [N][K] bf16
    prep_b_kernel<<<dim3(NDIM / 128, KDIM / 128), 256, 0, stream>>>(w, sc, bt);
    gemm_kernel<<<(MDIM / BM) * (NDIM / BN), 256, 0, stream>>>(x, bt, out);
  } else {
    fallback_kernel<<<dim3(NDIM / 256, MDIM), 256, 0, stream>>>(x, w, sc, out);
  }
}